// Round 9
// baseline (487.431 us; speedup 1.0000x reference)
//
#include <hip/hip_runtime.h>
#include <cstdint>

// ---------------------------------------------------------------------------
// AnaphoricityScorer: scores = rough + FFNN([a, b, a*b, pw] @ W1 -> leaky -> W_out)
// Factorized: h = Ha[batch] + Hb[idx] + (a*b|pw)@W1cd + b1
// R9: main GEMM = WAVE-INDEPENDENT, zero LDS, zero barriers. Each wave owns a
//     64x128 strip: 4 A-frags direct from P, 8 B-frags from L2-resident W1T,
//     K fully unrolled (34 steps, const offset: immediates). R4-R8 showed all
//     barrier-locked schedules pin at 16-22% MfmaUtil with no resource
//     saturated (convoy effect); this removes the convoy entirely and lets
//     the compiler's own counted-vmcnt scheduling (m97-verified) pipeline.
// ---------------------------------------------------------------------------

typedef short short8 __attribute__((ext_vector_type(8)));
typedef float f32x4 __attribute__((ext_vector_type(4)));

static __device__ __forceinline__ unsigned short f2bf(float x) {
  union { float f; unsigned u; } v; v.f = x;
  unsigned r = v.u + 0x7fffu + ((v.u >> 16) & 1u);  // RNE
  return (unsigned short)(r >> 16);
}
static __device__ __forceinline__ float bf2f(unsigned short u) {
  union { unsigned u; float f; } v; v.u = ((unsigned)u) << 16;
  return v.f;
}

static __device__ __forceinline__ void gload_lds16(const void* g, void* lds) {
  __builtin_amdgcn_global_load_lds(
      (const __attribute__((address_space(1))) void*)(unsigned long long)(uintptr_t)g,
      (__attribute__((address_space(3))) void*)(unsigned)(uintptr_t)lds, 16, 0, 0);
}

// W1 [3136][1024] f32 -> W1T [1024][3136] bf16 (tiled transpose)
__global__ void k_w1t(const float* __restrict__ W1, unsigned short* __restrict__ W1T) {
  __shared__ float t[64][65];
  int k0 = blockIdx.x * 64, n0 = blockIdx.y * 64;
  int c = threadIdx.x & 63, r4 = threadIdx.x >> 6;
#pragma unroll
  for (int rr = 0; rr < 16; ++rr) {
    int r = rr * 4 + r4;
    t[r][c] = W1[(size_t)(k0 + r) * 1024 + n0 + c];
  }
  __syncthreads();
#pragma unroll
  for (int rr = 0; rr < 16; ++rr) {
    int r = rr * 4 + r4;
    W1T[(size_t)(n0 + r) * 3136 + k0 + c] = f2bf(t[c][r]);
  }
}

__global__ void k_cvt(const float* __restrict__ s, unsigned short* __restrict__ d, int n4) {
  int i = blockIdx.x * 256 + threadIdx.x;
  if (i < n4) {
    float4 v = ((const float4*)s)[i];
    ushort4 o; o.x = f2bf(v.x); o.y = f2bf(v.y); o.z = f2bf(v.z); o.w = f2bf(v.w);
    ((ushort4*)d)[i] = o;
  }
}

// P[p] = [ bf16(a)*bf16(b) (1024) | bf16(pw) (64) ]; 1 block per batch row.
__global__ void k_pairs(const unsigned short* __restrict__ Abm,
                        const unsigned short* __restrict__ Aball,
                        const float* __restrict__ pw, const int* __restrict__ idx,
                        unsigned short* __restrict__ P) {
  int b = blockIdx.x, tid = threadIdx.x;
  ushort4 av = ((const ushort4*)(Abm + (size_t)b * 1024))[tid];
  float a0 = bf2f(av.x), a1 = bf2f(av.y), a2 = bf2f(av.z), a3 = bf2f(av.w);
  for (int j = 0; j < 50; ++j) {
    int p = b * 50 + j;
    int g = idx[p];
    ushort4 bv = ((const ushort4*)(Aball + (size_t)g * 1024))[tid];
    ushort4 o;
    o.x = f2bf(a0 * bf2f(bv.x));
    o.y = f2bf(a1 * bf2f(bv.y));
    o.z = f2bf(a2 * bf2f(bv.z));
    o.w = f2bf(a3 * bf2f(bv.w));
    ((ushort4*)(P + (size_t)p * 1088))[tid] = o;
    if (tid < 16) {
      float4 pv = ((const float4*)(pw + (size_t)p * 64))[tid];
      ushort4 q; q.x = f2bf(pv.x); q.y = f2bf(pv.y); q.z = f2bf(pv.z); q.w = f2bf(pv.w);
      ((ushort4*)(P + (size_t)p * 1088 + 1024))[tid] = q;
    }
  }
}

// 128x128 GEMM (Ha, Hb): counted-vmcnt pipeline + XOR swizzle (R6, working).
__global__ __launch_bounds__(256) void k_gemm0(
    const unsigned short* __restrict__ A, int ldaE, int K,
    const unsigned short* __restrict__ W1T, int koff, float* __restrict__ C) {
  __shared__ unsigned short As[2][8192];
  __shared__ unsigned short Bs[2][8192];
  int tid = threadIdx.x, lane = tid & 63, wave = tid >> 6;
  int row0 = blockIdx.x * 128, n0 = blockIdx.y * 128;
  int wr = wave >> 1, wc = wave & 1;
  int llo = lane & 15, lhi = lane >> 4;
  f32x4 acc[4][4] = {};
  const char* Ab = (const char*)A;
  const char* Bb = (const char*)W1T + (size_t)koff * 2;
  size_t ldaB = (size_t)ldaE * 2;
  int nkt = K >> 6;
  int grow = tid >> 3;  // 0..31
  int j16 = (((tid & 7) ^ (grow & 7)) << 4);

  auto stage = [&](int b, int kt) {
#pragma unroll
    for (int r2 = 0; r2 < 4; ++r2) {
      gload_lds16(Ab + (size_t)(row0 + r2 * 32 + grow) * ldaB + (size_t)kt * 128 + j16,
                  (char*)(&As[b][0]) + r2 * 4096 + tid * 16);
      gload_lds16(Bb + (size_t)(n0 + r2 * 32 + grow) * 6272 + (size_t)kt * 128 + j16,
                  (char*)(&Bs[b][0]) + r2 * 4096 + tid * 16);
    }
  };

  stage(0, 0);
  for (int kt = 0; kt < nkt; ++kt) {
    int cur = kt & 1;
    __builtin_amdgcn_s_barrier();
    __builtin_amdgcn_sched_barrier(0);
    if (kt + 1 < nkt) {
      stage(cur ^ 1, kt + 1);
      asm volatile("s_waitcnt vmcnt(8)" ::: "memory");
    } else {
      asm volatile("s_waitcnt vmcnt(0)" ::: "memory");
    }
    __builtin_amdgcn_s_barrier();
    __builtin_amdgcn_sched_barrier(0);
    const char* as = (const char*)(&As[cur][0]);
    const char* bs = (const char*)(&Bs[cur][0]);
    short8 bfr[4][2];
#pragma unroll
    for (int n = 0; n < 4; ++n)
#pragma unroll
      for (int ks = 0; ks < 2; ++ks) {
        int row = wc * 64 + n * 16 + llo;
        int j = ((ks << 2) | lhi) ^ (llo & 7);
        bfr[n][ks] = *(const short8*)(bs + row * 128 + j * 16);
      }
#pragma unroll
    for (int m = 0; m < 4; ++m) {
      short8 af[2];
#pragma unroll
      for (int ks = 0; ks < 2; ++ks) {
        int row = wr * 64 + m * 16 + llo;
        int j = ((ks << 2) | lhi) ^ (llo & 7);
        af[ks] = *(const short8*)(as + row * 128 + j * 16);
      }
#pragma unroll
      for (int n = 0; n < 4; ++n)
#pragma unroll
        for (int ks = 0; ks < 2; ++ks)
          acc[m][n] = __builtin_amdgcn_mfma_f32_16x16x32_bf16(af[ks], bfr[n][ks], acc[m][n], 0, 0, 0);
    }
  }
#pragma unroll
  for (int m = 0; m < 4; ++m)
#pragma unroll
    for (int i = 0; i < 4; ++i) {
      int tr = wr * 64 + m * 16 + lhi * 4 + i;
#pragma unroll
      for (int n = 0; n < 4; ++n)
        C[(size_t)(row0 + tr) * 1024 + n0 + wc * 64 + n * 16 + llo] = acc[m][n][i];
    }
}

// Main GEMM, wave-independent: each wave owns 64 rows x 128 cols. No LDS, no
// barriers. Grid 1600 = 200 row-blocks(256 rows) x 8 y-tiles, XCD swizzle.
__global__ __launch_bounds__(256, 2) void k_mainwi(
    const unsigned short* __restrict__ P, const unsigned short* __restrict__ W1T,
    float* __restrict__ partial,
    const float* __restrict__ Ha, const float* __restrict__ Hb,
    const float* __restrict__ b1, const float* __restrict__ Wout,
    const int* __restrict__ idx) {
  int tid = threadIdx.x, lane = tid & 63, wave = tid >> 6;
  int llo = lane & 15, lhi = lane >> 4;
  int id = blockIdx.x;
  int r = id >> 3;                       // 0..199
  int x = (id & 7) * 25 + (r >> 3);      // 25 row-blocks per XCD chunk
  int y = r & 7;                         // y fastest within chunk
  int row0 = x * 256 + wave * 64;
  int n0 = y * 128;

  // per-lane fragment base pointers (bytes)
  const char* pa[4];
  const char* pb[8];
#pragma unroll
  for (int m = 0; m < 4; ++m)
    pa[m] = (const char*)P + (size_t)(row0 + m * 16 + llo) * 2176 + lhi * 16;
#pragma unroll
  for (int n = 0; n < 8; ++n)
    pb[n] = (const char*)W1T + (size_t)(n0 + n * 16 + llo) * 6272 + 4096 + lhi * 16;

  f32x4 acc[4][8] = {};
#pragma unroll
  for (int kt = 0; kt < 34; ++kt) {
    short8 a[4], b[8];
#pragma unroll
    for (int m = 0; m < 4; ++m) a[m] = *(const short8*)(pa[m] + kt * 64);
#pragma unroll
    for (int n = 0; n < 8; ++n) b[n] = *(const short8*)(pb[n] + kt * 64);
#pragma unroll
    for (int m = 0; m < 4; ++m)
#pragma unroll
      for (int n = 0; n < 8; ++n)
        acc[m][n] = __builtin_amdgcn_mfma_f32_16x16x32_bf16(a[m], b[n], acc[m][n], 0, 0, 0);
  }

  // fused epilogue -> partial[p][16]; two 64-col chunks (n 0-3, 4-7)
  float b1v[8], wov[8];
  int coln[8];
#pragma unroll
  for (int n = 0; n < 8; ++n) {
    coln[n] = n0 + n * 16 + llo;
    b1v[n] = b1[coln[n]];
    wov[n] = Wout[coln[n]];
  }
#pragma unroll
  for (int m = 0; m < 4; ++m)
#pragma unroll
    for (int i = 0; i < 4; ++i) {
      int p = row0 + m * 16 + lhi * 4 + i;
      int bb = p / 50;
      int gg = idx[p];
      const float* Har = Ha + (size_t)bb * 1024;
      const float* Hbr = Hb + (size_t)gg * 1024;
      float s0 = 0.f, s1 = 0.f;
#pragma unroll
      for (int n = 0; n < 4; ++n) {
        float h = acc[m][n][i] + Har[coln[n]] + Hbr[coln[n]] + b1v[n];
        h = h > 0.f ? h : 0.01f * h;
        s0 += h * wov[n];
      }
#pragma unroll
      for (int n = 4; n < 8; ++n) {
        float h = acc[m][n][i] + Har[coln[n]] + Hbr[coln[n]] + b1v[n];
        h = h > 0.f ? h : 0.01f * h;
        s1 += h * wov[n];
      }
      s0 += __shfl_xor(s0, 1, 64);
      s0 += __shfl_xor(s0, 2, 64);
      s0 += __shfl_xor(s0, 4, 64);
      s0 += __shfl_xor(s0, 8, 64);
      s1 += __shfl_xor(s1, 1, 64);
      s1 += __shfl_xor(s1, 2, 64);
      s1 += __shfl_xor(s1, 4, 64);
      s1 += __shfl_xor(s1, 8, 64);
      if (llo == 0) {
        partial[(size_t)p * 16 + y * 2 + 0] = s0;
        partial[(size_t)p * 16 + y * 2 + 1] = s1;
      }
    }
}

__global__ void k_final(const float* __restrict__ partial, const float* __restrict__ rough,
                        const float* __restrict__ bout, float* __restrict__ out) {
  int t = blockIdx.x * 256 + threadIdx.x;
  if (t < 51200) {
    float s = rough[t] + bout[0];
    const float* pp = partial + (size_t)t * 16;
#pragma unroll
    for (int c = 0; c < 16; ++c) s += pp[c];
    out[(size_t)(t / 50) * 51 + 1 + (t % 50)] = s;
  }
  if (t < 1024) out[(size_t)t * 51] = 1e-7f;
}

extern "C" void kernel_launch(void* const* d_in, const int* in_sizes, int n_in,
                              void* d_out, int out_size, void* d_ws, size_t ws_size,
                              hipStream_t stream) {
  (void)in_sizes; (void)n_in; (void)out_size;
  const float* allm  = (const float*)d_in[0];  // [8192][1024]
  const float* am    = (const float*)d_in[1];  // [1024][1024]
  const float* pw    = (const float*)d_in[2];  // [1024][50][64]
  const float* rough = (const float*)d_in[3];  // [1024][50]
  const float* W1    = (const float*)d_in[4];  // [3136][1024]
  const float* b1    = (const float*)d_in[5];  // [1024]
  const float* Wout  = (const float*)d_in[6];  // [1024]
  const float* bout  = (const float*)d_in[7];  // [1]
  const int*   idx   = (const int*)d_in[8];    // [1024][50]
  float* out = (float*)d_out;                  // [1024][51]

  char* w = (char*)d_ws;
  unsigned short* W1T   = (unsigned short*)w; w += (size_t)1024 * 3136 * 2;
  unsigned short* Abm   = (unsigned short*)w; w += (size_t)1024 * 1024 * 2;
  unsigned short* Aball = (unsigned short*)w; w += (size_t)8192 * 1024 * 2;
  unsigned short* P     = (unsigned short*)w; w += (size_t)51200 * 1088 * 2;
  float* Ha             = (float*)w;          w += (size_t)1024 * 1024 * 4;
  float* Hb             = (float*)w;          w += (size_t)8192 * 1024 * 4;
  float* part           = (float*)w;          w += (size_t)51200 * 16 * 4;
  size_t need = (size_t)(w - (char*)d_ws);
  if (ws_size < need) return;

  k_w1t<<<dim3(49, 16), 256, 0, stream>>>(W1, W1T);
  k_cvt<<<dim3(1024), 256, 0, stream>>>(am, Abm, 1024 * 1024 / 4);
  k_cvt<<<dim3(8192), 256, 0, stream>>>(allm, Aball, 8192 * 1024 / 4);
  k_pairs<<<dim3(1024), 256, 0, stream>>>(Abm, Aball, pw, idx, P);
  k_gemm0<<<dim3(8, 8), 256, 0, stream>>>(Abm, 1024, 1024, W1T, 0, Ha);
  k_gemm0<<<dim3(64, 8), 256, 0, stream>>>(Aball, 1024, 1024, W1T, 1024, Hb);
  k_mainwi<<<dim3(1600), 256, 0, stream>>>(P, W1T, part, Ha, Hb, b1, Wout, idx);
  k_final<<<dim3(200), 256, 0, stream>>>(part, rough, bout, out);
}

// Round 10
// 286.319 us; speedup vs baseline: 1.7024x; 1.7024x over previous
//
#include <hip/hip_runtime.h>
#include <cstdint>

// ---------------------------------------------------------------------------
// AnaphoricityScorer: scores = rough + FFNN([a, b, a*b, pw] @ W1 -> leaky -> W_out)
// Factorized: h = Ha[batch] + Hb[idx] + (a*b|pw)@W1cd + b1
// R10: main GEMM = wave-independent + PRE-PACKED OPERANDS.
//   P and B stored in MFMA-fragment order: tile[rt][kc][lane][8] with
//   lane = (row%16) + 16*((k%32)>>3), elem = k%8  (verified frag mapping).
//   Every A/B fragment = ONE coalesced 1KB global load (base + lane*16).
//   No LDS, no barriers; explicit 2-stage register ping-pong; 4 waves/block
//   share the B panel via L1; 2 blocks/CU. R9 failed on 16-line gathers --
//   this makes every load contiguous. W1T split: row-major [1024][2048] for
//   Ha/Hb GEMMs, tiled Bt (2.2MB) for main; same total workspace.
// ---------------------------------------------------------------------------

typedef short short8 __attribute__((ext_vector_type(8)));
typedef float f32x4 __attribute__((ext_vector_type(4)));

#define RT_STRIDE 34816  // 34 kc * 1024 B per 16-row fragment tile

static __device__ __forceinline__ unsigned short f2bf(float x) {
  union { float f; unsigned u; } v; v.f = x;
  unsigned r = v.u + 0x7fffu + ((v.u >> 16) & 1u);  // RNE
  return (unsigned short)(r >> 16);
}
static __device__ __forceinline__ float bf2f(unsigned short u) {
  union { unsigned u; float f; } v; v.u = ((unsigned)u) << 16;
  return v.f;
}

static __device__ __forceinline__ void gload_lds16(const void* g, void* lds) {
  __builtin_amdgcn_global_load_lds(
      (const __attribute__((address_space(1))) void*)(unsigned long long)(uintptr_t)g,
      (__attribute__((address_space(3))) void*)(unsigned)(uintptr_t)lds, 16, 0, 0);
}

// W1 [3136][1024] f32 -> W1T2 [1024][2048] bf16 (k<2048, row-major, for gemm0)
//                     -> Bt tiled [64 ct][34 kc][64 lane][8] (k>=2048, for main)
__global__ void k_w1t(const float* __restrict__ W1, unsigned short* __restrict__ W1T2,
                      unsigned short* __restrict__ Bt) {
  __shared__ float t[64][65];
  int k0 = blockIdx.x * 64, n0 = blockIdx.y * 64;
  int c = threadIdx.x & 63, r4 = threadIdx.x >> 6;
#pragma unroll
  for (int rr = 0; rr < 16; ++rr) {
    int r = rr * 4 + r4;
    t[r][c] = W1[(size_t)(k0 + r) * 1024 + n0 + c];  // t[k-local][col-local]
  }
  __syncthreads();
  if (k0 < 2048) {
#pragma unroll
    for (int rr = 0; rr < 16; ++rr) {
      int r = rr * 4 + r4;
      W1T2[(size_t)(n0 + r) * 2048 + k0 + c] = f2bf(t[c][r]);
    }
  } else {
    int kb = k0 - 2048;
#pragma unroll
    for (int qq = 0; qq < 2; ++qq) {
      int q = threadIdx.x * 2 + qq;   // 0..511
      int cc = q >> 3, rg = q & 7;    // col-local, k-octet
      short8 v;
#pragma unroll
      for (int e = 0; e < 8; ++e) v[e] = (short)f2bf(t[rg * 8 + e][cc]);
      int ct = (n0 + cc) >> 4;
      int kc = (kb >> 5) + (rg >> 2);
      int ln = (cc & 15) + ((rg & 3) << 4);
      *(short8*)((char*)Bt + (size_t)ct * RT_STRIDE + kc * 1024 + ln * 16) = v;
    }
  }
}

__global__ void k_cvt(const float* __restrict__ s, unsigned short* __restrict__ d, int n4) {
  int i = blockIdx.x * 256 + threadIdx.x;
  if (i < n4) {
    float4 v = ((const float4*)s)[i];
    ushort4 o; o.x = f2bf(v.x); o.y = f2bf(v.y); o.z = f2bf(v.z); o.w = f2bf(v.w);
    ((ushort4*)d)[i] = o;
  }
}

// Pt tiled: Pt[rt][kc][lane][8], pair p = row, k = [a*b (1024) | pw (64)].
// Block per batch row b; all threads share p per j-iteration (coalesced reads).
__global__ void k_pairs(const unsigned short* __restrict__ Abm,
                        const unsigned short* __restrict__ Aball,
                        const float* __restrict__ pw, const int* __restrict__ idx,
                        unsigned short* __restrict__ Pt) {
  int b = blockIdx.x, t = threadIdx.x;
  int k0 = t * 4;
  ushort4 av = *(const ushort4*)(Abm + (size_t)b * 1024 + k0);
  float a0 = bf2f(av.x), a1 = bf2f(av.y), a2 = bf2f(av.z), a3 = bf2f(av.w);
  int kc = k0 >> 5;
  int lnk = ((k0 & 31) >> 3) << 4;
  int e2 = (k0 & 7) * 2;
  for (int j = 0; j < 50; ++j) {
    int p = b * 50 + j;
    int g = idx[p];
    char* base = (char*)Pt + (size_t)(p >> 4) * RT_STRIDE;
    int pf = p & 15;
    ushort4 bv = *(const ushort4*)(Aball + (size_t)g * 1024 + k0);
    ushort4 o;
    o.x = f2bf(a0 * bf2f(bv.x));
    o.y = f2bf(a1 * bf2f(bv.y));
    o.z = f2bf(a2 * bf2f(bv.z));
    o.w = f2bf(a3 * bf2f(bv.w));
    *(ushort4*)(base + kc * 1024 + (pf + lnk) * 16 + e2) = o;
    if (t < 16) {
      int q0 = t * 4;
      float4 pv = *(const float4*)(pw + (size_t)p * 64 + q0);
      ushort4 qo; qo.x = f2bf(pv.x); qo.y = f2bf(pv.y); qo.z = f2bf(pv.z); qo.w = f2bf(pv.w);
      int kcq = 32 + (q0 >> 5);
      int lnq = pf + (((q0 & 31) >> 3) << 4);
      *(ushort4*)(base + kcq * 1024 + lnq * 16 + (q0 & 7) * 2) = qo;
    }
  }
}

// 128x128 GEMM (Ha, Hb): counted-vmcnt + XOR swizzle (R6, verified). B from
// W1T2 row-major stride 2048 elems.
__global__ __launch_bounds__(256) void k_gemm0(
    const unsigned short* __restrict__ A, int ldaE, int K,
    const unsigned short* __restrict__ W1T2, int koff, float* __restrict__ C) {
  __shared__ unsigned short As[2][8192];
  __shared__ unsigned short Bs[2][8192];
  int tid = threadIdx.x, lane = tid & 63, wave = tid >> 6;
  int row0 = blockIdx.x * 128, n0 = blockIdx.y * 128;
  int wr = wave >> 1, wc = wave & 1;
  int llo = lane & 15, lhi = lane >> 4;
  f32x4 acc[4][4] = {};
  const char* Ab = (const char*)A;
  const char* Bb = (const char*)W1T2 + (size_t)koff * 2;
  size_t ldaB = (size_t)ldaE * 2;
  int nkt = K >> 6;
  int grow = tid >> 3;
  int j16 = (((tid & 7) ^ (grow & 7)) << 4);

  auto stage = [&](int b, int kt) {
#pragma unroll
    for (int r2 = 0; r2 < 4; ++r2) {
      gload_lds16(Ab + (size_t)(row0 + r2 * 32 + grow) * ldaB + (size_t)kt * 128 + j16,
                  (char*)(&As[b][0]) + r2 * 4096 + tid * 16);
      gload_lds16(Bb + (size_t)(n0 + r2 * 32 + grow) * 4096 + (size_t)kt * 128 + j16,
                  (char*)(&Bs[b][0]) + r2 * 4096 + tid * 16);
    }
  };

  stage(0, 0);
  for (int kt = 0; kt < nkt; ++kt) {
    int cur = kt & 1;
    __builtin_amdgcn_s_barrier();
    __builtin_amdgcn_sched_barrier(0);
    if (kt + 1 < nkt) {
      stage(cur ^ 1, kt + 1);
      asm volatile("s_waitcnt vmcnt(8)" ::: "memory");
    } else {
      asm volatile("s_waitcnt vmcnt(0)" ::: "memory");
    }
    __builtin_amdgcn_s_barrier();
    __builtin_amdgcn_sched_barrier(0);
    const char* as = (const char*)(&As[cur][0]);
    const char* bs = (const char*)(&Bs[cur][0]);
    short8 bfr[4][2];
#pragma unroll
    for (int n = 0; n < 4; ++n)
#pragma unroll
      for (int ks = 0; ks < 2; ++ks) {
        int row = wc * 64 + n * 16 + llo;
        int j = ((ks << 2) | lhi) ^ (llo & 7);
        bfr[n][ks] = *(const short8*)(bs + row * 128 + j * 16);
      }
#pragma unroll
    for (int m = 0; m < 4; ++m) {
      short8 af[2];
#pragma unroll
      for (int ks = 0; ks < 2; ++ks) {
        int row = wr * 64 + m * 16 + llo;
        int j = ((ks << 2) | lhi) ^ (llo & 7);
        af[ks] = *(const short8*)(as + row * 128 + j * 16);
      }
#pragma unroll
      for (int n = 0; n < 4; ++n)
#pragma unroll
        for (int ks = 0; ks < 2; ++ks)
          acc[m][n] = __builtin_amdgcn_mfma_f32_16x16x32_bf16(af[ks], bfr[n][ks], acc[m][n], 0, 0, 0);
    }
  }
#pragma unroll
  for (int m = 0; m < 4; ++m)
#pragma unroll
    for (int i = 0; i < 4; ++i) {
      int tr = wr * 64 + m * 16 + lhi * 4 + i;
#pragma unroll
      for (int n = 0; n < 4; ++n)
        C[(size_t)(row0 + tr) * 1024 + n0 + wc * 64 + n * 16 + llo] = acc[m][n][i];
    }
}

// Main GEMM: wave-independent, pre-packed operands, no LDS/barriers.
// Wave owns 64 rows x 128 cols. Grid 1600 = 200 x 8y, XCD swizzle.
__global__ __launch_bounds__(256, 2) void k_maint(
    const unsigned short* __restrict__ Pt, const unsigned short* __restrict__ Bt,
    float* __restrict__ partial,
    const float* __restrict__ Ha, const float* __restrict__ Hb,
    const float* __restrict__ b1, const float* __restrict__ Wout,
    const int* __restrict__ idx) {
  int tid = threadIdx.x, lane = tid & 63, wave = tid >> 6;
  int llo = lane & 15, lhi = lane >> 4;
  int id = blockIdx.x;
  int r = id >> 3;
  int x = (id & 7) * 25 + (r >> 3);
  int y = r & 7;
  int row0 = x * 256 + wave * 64;
  int n0 = y * 128;
  const char* pa = (const char*)Pt + (size_t)(row0 >> 4) * RT_STRIDE + lane * 16;
  const char* pb = (const char*)Bt + (size_t)(n0 >> 4) * RT_STRIDE + lane * 16;

  f32x4 acc[4][8] = {};
  short8 aA[4], bA[8], aB[4], bB[8];
#pragma unroll
  for (int m = 0; m < 4; ++m) aA[m] = *(const short8*)(pa + (size_t)m * RT_STRIDE);
#pragma unroll
  for (int n = 0; n < 8; ++n) bA[n] = *(const short8*)(pb + (size_t)n * RT_STRIDE);
  for (int kt = 0; kt < 34; kt += 2) {
#pragma unroll
    for (int m = 0; m < 4; ++m)
      aB[m] = *(const short8*)(pa + (size_t)m * RT_STRIDE + (kt + 1) * 1024);
#pragma unroll
    for (int n = 0; n < 8; ++n)
      bB[n] = *(const short8*)(pb + (size_t)n * RT_STRIDE + (kt + 1) * 1024);
#pragma unroll
    for (int m = 0; m < 4; ++m)
#pragma unroll
      for (int n = 0; n < 8; ++n)
        acc[m][n] = __builtin_amdgcn_mfma_f32_16x16x32_bf16(aA[m], bA[n], acc[m][n], 0, 0, 0);
    if (kt + 2 < 34) {
#pragma unroll
      for (int m = 0; m < 4; ++m)
        aA[m] = *(const short8*)(pa + (size_t)m * RT_STRIDE + (kt + 2) * 1024);
#pragma unroll
      for (int n = 0; n < 8; ++n)
        bA[n] = *(const short8*)(pb + (size_t)n * RT_STRIDE + (kt + 2) * 1024);
    }
#pragma unroll
    for (int m = 0; m < 4; ++m)
#pragma unroll
      for (int n = 0; n < 8; ++n)
        acc[m][n] = __builtin_amdgcn_mfma_f32_16x16x32_bf16(aB[m], bB[n], acc[m][n], 0, 0, 0);
  }

  // fused epilogue -> partial[p][16]; chunks y*2, y*2+1
  float b1v[8], wov[8];
  int coln[8];
#pragma unroll
  for (int n = 0; n < 8; ++n) {
    coln[n] = n0 + n * 16 + llo;
    b1v[n] = b1[coln[n]];
    wov[n] = Wout[coln[n]];
  }
#pragma unroll
  for (int m = 0; m < 4; ++m)
#pragma unroll
    for (int i = 0; i < 4; ++i) {
      int p = row0 + m * 16 + lhi * 4 + i;
      int bb = p / 50;
      int gg = idx[p];
      const float* Har = Ha + (size_t)bb * 1024;
      const float* Hbr = Hb + (size_t)gg * 1024;
      float s0 = 0.f, s1 = 0.f;
#pragma unroll
      for (int n = 0; n < 4; ++n) {
        float h = acc[m][n][i] + Har[coln[n]] + Hbr[coln[n]] + b1v[n];
        h = h > 0.f ? h : 0.01f * h;
        s0 += h * wov[n];
      }
#pragma unroll
      for (int n = 4; n < 8; ++n) {
        float h = acc[m][n][i] + Har[coln[n]] + Hbr[coln[n]] + b1v[n];
        h = h > 0.f ? h : 0.01f * h;
        s1 += h * wov[n];
      }
      s0 += __shfl_xor(s0, 1, 64);
      s0 += __shfl_xor(s0, 2, 64);
      s0 += __shfl_xor(s0, 4, 64);
      s0 += __shfl_xor(s0, 8, 64);
      s1 += __shfl_xor(s1, 1, 64);
      s1 += __shfl_xor(s1, 2, 64);
      s1 += __shfl_xor(s1, 4, 64);
      s1 += __shfl_xor(s1, 8, 64);
      if (llo == 0) {
        partial[(size_t)p * 16 + y * 2 + 0] = s0;
        partial[(size_t)p * 16 + y * 2 + 1] = s1;
      }
    }
}

__global__ void k_final(const float* __restrict__ partial, const float* __restrict__ rough,
                        const float* __restrict__ bout, float* __restrict__ out) {
  int t = blockIdx.x * 256 + threadIdx.x;
  if (t < 51200) {
    float s = rough[t] + bout[0];
    const float* pp = partial + (size_t)t * 16;
#pragma unroll
    for (int c = 0; c < 16; ++c) s += pp[c];
    out[(size_t)(t / 50) * 51 + 1 + (t % 50)] = s;
  }
  if (t < 1024) out[(size_t)t * 51] = 1e-7f;
}

extern "C" void kernel_launch(void* const* d_in, const int* in_sizes, int n_in,
                              void* d_out, int out_size, void* d_ws, size_t ws_size,
                              hipStream_t stream) {
  (void)in_sizes; (void)n_in; (void)out_size;
  const float* allm  = (const float*)d_in[0];  // [8192][1024]
  const float* am    = (const float*)d_in[1];  // [1024][1024]
  const float* pw    = (const float*)d_in[2];  // [1024][50][64]
  const float* rough = (const float*)d_in[3];  // [1024][50]
  const float* W1    = (const float*)d_in[4];  // [3136][1024]
  const float* b1    = (const float*)d_in[5];  // [1024]
  const float* Wout  = (const float*)d_in[6];  // [1024]
  const float* bout  = (const float*)d_in[7];  // [1]
  const int*   idx   = (const int*)d_in[8];    // [1024][50]
  float* out = (float*)d_out;                  // [1024][51]

  char* w = (char*)d_ws;
  unsigned short* W1T2  = (unsigned short*)w; w += (size_t)1024 * 2048 * 2;
  unsigned short* Bt    = (unsigned short*)w; w += (size_t)64 * RT_STRIDE;
  unsigned short* Abm   = (unsigned short*)w; w += (size_t)1024 * 1024 * 2;
  unsigned short* Aball = (unsigned short*)w; w += (size_t)8192 * 1024 * 2;
  unsigned short* Pt    = (unsigned short*)w; w += (size_t)3200 * RT_STRIDE;
  float* Ha             = (float*)w;          w += (size_t)1024 * 1024 * 4;
  float* Hb             = (float*)w;          w += (size_t)8192 * 1024 * 4;
  float* part           = (float*)w;          w += (size_t)51200 * 16 * 4;
  size_t need = (size_t)(w - (char*)d_ws);
  if (ws_size < need) return;

  k_w1t<<<dim3(49, 16), 256, 0, stream>>>(W1, W1T2, Bt);
  k_cvt<<<dim3(1024), 256, 0, stream>>>(am, Abm, 1024 * 1024 / 4);
  k_cvt<<<dim3(8192), 256, 0, stream>>>(allm, Aball, 8192 * 1024 / 4);
  k_pairs<<<dim3(1024), 256, 0, stream>>>(Abm, Aball, pw, idx, Pt);
  k_gemm0<<<dim3(8, 8), 256, 0, stream>>>(Abm, 1024, 1024, W1T2, 0, Ha);
  k_gemm0<<<dim3(64, 8), 256, 0, stream>>>(Aball, 1024, 1024, W1T2, 1024, Hb);
  k_maint<<<dim3(1600), 256, 0, stream>>>(Pt, Bt, part, Ha, Hb, b1, Wout, idx);
  k_final<<<dim3(200), 256, 0, stream>>>(part, rough, bout, out);
}